// Round 1
// baseline (91702.924 us; speedup 1.0000x reference)
//
#include <hip/hip_runtime.h>
#include <hip/hip_bf16.h>
#include <cstdint>
#include <cstddef>

#define T_LEN 16384
#define ETS 4
#define C1T 1796          // per-timestep stride of c1 LDS (32*7*8 + 4 pad -> bank-spread)
#define LNWG 8

// ---------------- prep: transposes + bias sums ----------------
__global__ void prep_kernel(const float* __restrict__ obs_w,
                            const float* __restrict__ wih0,
                            const float* __restrict__ wih1,
                            const float* __restrict__ bih0, const float* __restrict__ bhh0,
                            const float* __restrict__ bih1, const float* __restrict__ bhh1,
                            float* __restrict__ obs_wT,   // [1600][128]
                            float* __restrict__ wih0T,    // [192][1024], zero-padded k>=177
                            float* __restrict__ wih1T,    // [256][1024]
                            float* __restrict__ bias0, float* __restrict__ bias1) {
  int i = blockIdx.x * blockDim.x + threadIdx.x;   // grid covers 262144
  if (i < 1600 * 128) { int k = i >> 7, o = i & 127; obs_wT[i] = obs_w[o * 1600 + k]; }
  if (i < 192 * 1024) { int k = i >> 10, n = i & 1023; wih0T[i] = (k < 177) ? wih0[n * 177 + k] : 0.f; }
  if (i < 256 * 1024) { int k = i >> 10, n = i & 1023; wih1T[i] = wih1[n * 256 + k]; }
  if (i < 1024) { bias0[i] = bih0[i] + bhh0[i]; bias1[i] = bih1[i] + bhh1[i]; }
}

// ---------------- encoder: conv1+conv2+obs/pos/opp/act/cost -> feat[T][192] ----------------
__global__ __launch_bounds__(256) void encoder_kernel(
    const float* __restrict__ fov, const float* __restrict__ own_pos,
    const float* __restrict__ opponent, const float* __restrict__ cost,
    const int* __restrict__ action,
    const float* __restrict__ w1, const float* __restrict__ b1,
    const float* __restrict__ w2, const float* __restrict__ b2,
    const float* __restrict__ obs_wT, const float* __restrict__ obs_b,
    const float* __restrict__ pos_w, const float* __restrict__ pos_b,
    const float* __restrict__ opp_w, const float* __restrict__ opp_b,
    const float* __restrict__ act_emb,
    float* __restrict__ feat) {
  __shared__ float w1s[864];
  __shared__ float b1s[32];
  __shared__ float inp[ETS * 3 * 7 * 7];            // zero-padded 7x7 input planes
  __shared__ __align__(16) float c1[ETS * C1T];     // per t: [ic][7][8] zero-padded
  __shared__ __align__(16) float c2s[1600 * ETS];   // [k][t]
  __shared__ float red[4 * 128];
  int tid = threadIdx.x;
  int t0 = blockIdx.x * ETS;

  for (int i = tid; i < 864; i += 256) w1s[i] = w1[i];
  if (tid < 32) b1s[tid] = b1[tid];
  for (int i = tid; i < ETS * 3 * 49; i += 256) inp[i] = 0.f;
  for (int i = tid; i < ETS * C1T; i += 256) c1[i] = 0.f;
  __syncthreads();
  for (int i = tid; i < ETS * 75; i += 256) {
    int t = i / 75, r = i % 75;
    int y = r / 15, x = (r / 3) % 5, ch = r % 3;
    inp[((t * 3 + ch) * 7 + (y + 1)) * 7 + (x + 1)] = fov[(size_t)(t0 + t) * 75 + r];
  }
  __syncthreads();
  // conv1: 3->32, 3x3 SAME on 5x5
  for (int i = tid; i < ETS * 800; i += 256) {
    int t = i / 800, r = i % 800;
    int oc = r / 25, p = r % 25, y = p / 5, x = p % 5;
    float s = b1s[oc];
#pragma unroll
    for (int ch = 0; ch < 3; ++ch)
#pragma unroll
      for (int ky = 0; ky < 3; ++ky)
#pragma unroll
        for (int kx = 0; kx < 3; ++kx)
          s += inp[((t * 3 + ch) * 7 + y + ky) * 7 + x + kx] * w1s[oc * 27 + ch * 9 + ky * 3 + kx];
    c1[t * C1T + (oc * 7 + y + 1) * 8 + (x + 1)] = fmaxf(s, 0.f);
  }
  __syncthreads();
  // conv2: 32->64, 3x3 SAME; thread = (oc, t); plane held in regs
  {
    int oc = tid >> 2, tt = tid & 3;
    float acc[25];
    float bv = b2[oc];
#pragma unroll
    for (int p = 0; p < 25; ++p) acc[p] = bv;
    for (int ic = 0; ic < 32; ++ic) {
      float pl[56];
      const float* base = &c1[tt * C1T + ic * 56];
#pragma unroll
      for (int q = 0; q < 14; ++q) {
        float4 v = *(const float4*)(base + q * 4);
        pl[q * 4 + 0] = v.x; pl[q * 4 + 1] = v.y; pl[q * 4 + 2] = v.z; pl[q * 4 + 3] = v.w;
      }
      const float* wrow = &w2[(size_t)(oc * 32 + ic) * 9];
#pragma unroll
      for (int ky = 0; ky < 3; ++ky)
#pragma unroll
        for (int kx = 0; kx < 3; ++kx) {
          float wv = wrow[ky * 3 + kx];
#pragma unroll
          for (int p = 0; p < 25; ++p) {
            int y = p / 5, x = p % 5;
            acc[p] += pl[(y + ky) * 8 + (x + kx)] * wv;
          }
        }
    }
#pragma unroll
    for (int p = 0; p < 25; ++p)
      c2s[(oc * 25 + p) * ETS + tt] = fmaxf(acc[p], 0.f);
  }
  __syncthreads();
  // obs linear: 1600 -> 128, thread = (o, khalf)
  {
    int o = tid & 127, kh = tid >> 7;
    float a0 = 0, a1 = 0, a2 = 0, a3 = 0;
    for (int k = kh * 800; k < kh * 800 + 800; ++k) {
      float wv = obs_wT[k * 128 + o];
      float4 cv = *(const float4*)&c2s[k * ETS];
      a0 += cv.x * wv; a1 += cv.y * wv; a2 += cv.z * wv; a3 += cv.w * wv;
    }
    if (kh == 1) { red[0 * 128 + o] = a0; red[1 * 128 + o] = a1; red[2 * 128 + o] = a2; red[3 * 128 + o] = a3; }
    __syncthreads();
    if (kh == 0) {
      float ob = obs_b[o];
      float r0 = a0 + red[0 * 128 + o] + ob;
      float r1 = a1 + red[1 * 128 + o] + ob;
      float r2 = a2 + red[2 * 128 + o] + ob;
      float r3 = a3 + red[3 * 128 + o] + ob;
      feat[(size_t)(t0 + 0) * 192 + o] = r0;
      feat[(size_t)(t0 + 1) * 192 + o] = r1;
      feat[(size_t)(t0 + 2) * 192 + o] = r2;
      feat[(size_t)(t0 + 3) * 192 + o] = r3;
    }
  }
  // small features + zero pad (cols 128..191)
  if (tid < 64) {
    int t = tid >> 4, f = tid & 15;
    int ti = t0 + t;
    float px = own_pos[ti * 2 + 0] / 25.f, py = own_pos[ti * 2 + 1] / 25.f;
    float pe = pos_b[f] + px * pos_w[f * 2 + 0] + py * pos_w[f * 2 + 1];
    float o0 = opponent[ti * 3 + 0] / 25.f, o1 = opponent[ti * 3 + 1] / 25.f, o2 = opponent[ti * 3 + 2] / 150.f;
    float oe = opp_b[f] + o0 * opp_w[f * 3 + 0] + o1 * opp_w[f * 3 + 1] + o2 * opp_w[f * 3 + 2];
    float ae = act_emb[action[ti] * 16 + f];
    size_t fb = (size_t)ti * 192;
    feat[fb + 128 + f] = pe;
    feat[fb + 144 + f] = oe;
    feat[fb + 160 + f] = ae;
    if (f == 0) feat[fb + 176] = cost[ti];
    if (f < 15) feat[fb + 177 + f] = 0.f;
  }
}

// ---------------- fp32 tiled GEMM: C[M,N] = A[M,K] @ B[K,N] + bias[N] ----------------
__global__ __launch_bounds__(256) void gemm_bias_kernel(
    const float* __restrict__ A, const float* __restrict__ B,
    const float* __restrict__ bias, float* __restrict__ C,
    int M, int N, int K) {
  __shared__ __align__(16) float As[32][68];
  __shared__ __align__(16) float Bs[32][68];
  int tid = threadIdx.x;
  int mb = M >> 6;                       // power of two
  int bm = blockIdx.x & (mb - 1);
  int bn = blockIdx.x / mb;
  int tx = tid & 15, ty = tid >> 4;      // tx -> n, ty -> m
  float acc[4][4];
#pragma unroll
  for (int i = 0; i < 4; i++)
#pragma unroll
    for (int j = 0; j < 4; j++) acc[i][j] = 0.f;
  for (int k0 = 0; k0 < K; k0 += 32) {
#pragma unroll
    for (int i = 0; i < 2; ++i) {
      int id = tid + i * 256;
      int m = id >> 3, kq = id & 7;
      float4 v = *(const float4*)&A[(size_t)(bm * 64 + m) * K + k0 + kq * 4];
      As[kq * 4 + 0][m] = v.x; As[kq * 4 + 1][m] = v.y; As[kq * 4 + 2][m] = v.z; As[kq * 4 + 3][m] = v.w;
    }
#pragma unroll
    for (int i = 0; i < 2; ++i) {
      int id = tid + i * 256;
      int k = id >> 4, nq = id & 15;
      float4 v = *(const float4*)&B[(size_t)(k0 + k) * N + bn * 64 + nq * 4];
      *(float4*)&Bs[k][nq * 4] = v;
    }
    __syncthreads();
#pragma unroll
    for (int k = 0; k < 32; ++k) {
      float4 a4 = *(const float4*)&As[k][ty * 4];
      float4 b4 = *(const float4*)&Bs[k][tx * 4];
      float am[4] = {a4.x, a4.y, a4.z, a4.w};
      float bn4[4] = {b4.x, b4.y, b4.z, b4.w};
#pragma unroll
      for (int i = 0; i < 4; i++)
#pragma unroll
        for (int j = 0; j < 4; j++) acc[i][j] += am[i] * bn4[j];
    }
    __syncthreads();
  }
#pragma unroll
  for (int i = 0; i < 4; ++i) {
    int m = bm * 64 + ty * 4 + i;
    int n0 = bn * 64 + tx * 4;
    float4 o;
    o.x = acc[i][0] + bias[n0 + 0];
    o.y = acc[i][1] + bias[n0 + 1];
    o.z = acc[i][2] + bias[n0 + 2];
    o.w = acc[i][3] + bias[n0 + 3];
    *(float4*)&C[(size_t)m * N + n0] = o;
  }
}

// ---------------- persistent multi-workgroup LSTM layer ----------------
// 8 active wgs x 256 threads; thread = (unit j = g>>3, kslice ks = g&7).
// Each thread: 4 gate-rows x 32 weights in VGPRs; butterfly-reduce over ks.
// Cross-wg per-step sync: agent-scope atomic counter; h via double-buffered global.
__global__ __launch_bounds__(256) void lstm_layer_kernel(
    const float* __restrict__ pre, const float* __restrict__ whh,
    float* __restrict__ hs_out, float* __restrict__ hbuf,
    unsigned int* __restrict__ cnt,
    float* __restrict__ hfin, float* __restrict__ cfin,
    int write_hs) {
  if (blockIdx.x & 7) return;             // XCD-packing heuristic; correctness-independent
  int wg = blockIdx.x >> 3;               // 0..7
  int tid = threadIdx.x;
  int g = wg * 256 + tid;
  int j = g >> 3;
  int ks = g & 7;
  float w0[32], w1r[32], w2r[32], w3r[32];
  {
    const float* wb = whh + (size_t)j * 256 + ks * 32;
#pragma unroll
    for (int q = 0; q < 8; ++q) {
      float4 v;
      v = *(const float4*)(wb + 0 * 65536 + q * 4);
      w0[q * 4] = v.x; w0[q * 4 + 1] = v.y; w0[q * 4 + 2] = v.z; w0[q * 4 + 3] = v.w;
      v = *(const float4*)(wb + 1 * 65536 + q * 4);
      w1r[q * 4] = v.x; w1r[q * 4 + 1] = v.y; w1r[q * 4 + 2] = v.z; w1r[q * 4 + 3] = v.w;
      v = *(const float4*)(wb + 2 * 65536 + q * 4);
      w2r[q * 4] = v.x; w2r[q * 4 + 1] = v.y; w2r[q * 4 + 2] = v.z; w2r[q * 4 + 3] = v.w;
      v = *(const float4*)(wb + 3 * 65536 + q * 4);
      w3r[q * 4] = v.x; w3r[q * 4 + 1] = v.y; w3r[q * 4 + 2] = v.z; w3r[q * 4 + 3] = v.w;
    }
  }
  __shared__ __align__(16) float hl[8 * 40];   // stride 40: 2-way (free) LDS banks
  float c = 0.f;
  for (int t = 0; t < T_LEN; ++t) {
    // prefetch input projection before the spin (hides HBM latency)
    size_t pb = (size_t)t * 1024 + j;
    float p0 = pre[pb], p1 = pre[pb + 256], p2 = pre[pb + 512], p3 = pre[pb + 768];
    if (t > 0) {
      if (tid == 0) {
        while (__hip_atomic_load(&cnt[t - 1], __ATOMIC_ACQUIRE, __HIP_MEMORY_SCOPE_AGENT) < LNWG) { }
      }
      __syncthreads();
      float hv = __hip_atomic_load(&hbuf[(t & 1) * 256 + tid], __ATOMIC_RELAXED, __HIP_MEMORY_SCOPE_AGENT);
      hl[(tid >> 5) * 40 + (tid & 31)] = hv;
    } else {
      hl[(tid >> 5) * 40 + (tid & 31)] = 0.f;
    }
    __syncthreads();
    float h[32];
#pragma unroll
    for (int q = 0; q < 8; ++q) {
      float4 v = *(const float4*)&hl[ks * 40 + q * 4];
      h[q * 4] = v.x; h[q * 4 + 1] = v.y; h[q * 4 + 2] = v.z; h[q * 4 + 3] = v.w;
    }
    float a0 = 0, a1 = 0, a2 = 0, a3 = 0;
#pragma unroll
    for (int i = 0; i < 32; ++i) {
      a0 += w0[i] * h[i]; a1 += w1r[i] * h[i]; a2 += w2r[i] * h[i]; a3 += w3r[i] * h[i];
    }
#pragma unroll
    for (int m = 1; m < 8; m <<= 1) {
      a0 += __shfl_xor(a0, m); a1 += __shfl_xor(a1, m);
      a2 += __shfl_xor(a2, m); a3 += __shfl_xor(a3, m);
    }
    float zi = a0 + p0, zf = a1 + p1, zg = a2 + p2, zo = a3 + p3;
    float ig = 1.f / (1.f + __expf(-zi));
    float fg = 1.f / (1.f + __expf(-zf));
    float gg = 1.f - 2.f / (__expf(2.f * zg) + 1.f);
    float og = 1.f / (1.f + __expf(-zo));
    c = fg * c + ig * gg;
    float hn = og * (1.f - 2.f / (__expf(2.f * c) + 1.f));
    if (ks == 0) {
      __hip_atomic_store(&hbuf[((t + 1) & 1) * 256 + j], hn, __ATOMIC_RELAXED, __HIP_MEMORY_SCOPE_AGENT);
      if (write_hs) hs_out[(size_t)t * 256 + j] = hn;
      if (t == T_LEN - 1) { hfin[j] = hn; cfin[j] = c; }
    }
    asm volatile("s_waitcnt vmcnt(0)" ::: "memory");  // writers' stores at coherence point
    __syncthreads();
    if (tid == 0) __hip_atomic_fetch_add(&cnt[t], 1u, __ATOMIC_RELEASE, __HIP_MEMORY_SCOPE_AGENT);
  }
}

// ---------------- gather outputs ----------------
__global__ void finalize_kernel(const float* __restrict__ h0, const float* __restrict__ c0,
                                const float* __restrict__ h1, const float* __restrict__ c1,
                                float* __restrict__ out) {
  int i = blockIdx.x * blockDim.x + threadIdx.x;
  if (i < 256) out[i] = h1[i];
  else if (i < 512) out[i] = h0[i - 256];
  else if (i < 768) out[i] = h1[i - 512];
  else if (i < 1024) out[i] = c0[i - 768];
  else if (i < 1280) out[i] = c1[i - 1024];
}

extern "C" void kernel_launch(void* const* d_in, const int* in_sizes, int n_in,
                              void* d_out, int out_size, void* d_ws, size_t ws_size,
                              hipStream_t stream) {
  const float* fov      = (const float*)d_in[0];
  const float* own_pos  = (const float*)d_in[1];
  const float* opponent = (const float*)d_in[2];
  const float* cost     = (const float*)d_in[3];
  const int*   action   = (const int*)d_in[4];
  const float* conv1_w  = (const float*)d_in[5];
  const float* conv1_b  = (const float*)d_in[6];
  const float* conv2_w  = (const float*)d_in[7];
  const float* conv2_b  = (const float*)d_in[8];
  const float* obs_w    = (const float*)d_in[9];
  const float* obs_b    = (const float*)d_in[10];
  const float* pos_w    = (const float*)d_in[11];
  const float* pos_b    = (const float*)d_in[12];
  const float* opp_w    = (const float*)d_in[13];
  const float* opp_b    = (const float*)d_in[14];
  const float* act_emb  = (const float*)d_in[15];
  const float* wih0     = (const float*)d_in[16];
  const float* whh0     = (const float*)d_in[17];
  const float* bih0     = (const float*)d_in[18];
  const float* bhh0     = (const float*)d_in[19];
  const float* wih1     = (const float*)d_in[20];
  const float* whh1     = (const float*)d_in[21];
  const float* bih1     = (const float*)d_in[22];
  const float* bhh1     = (const float*)d_in[23];

  char* ws = (char*)d_ws;
  size_t off = 0;
  auto alloc = [&](size_t bytes) {
    void* p = ws + off;
    off += (bytes + 255) & ~(size_t)255;
    return p;
  };
  float* feat   = (float*)alloc((size_t)T_LEN * 192 * 4);   // 12.6 MB
  float* pre    = (float*)alloc((size_t)T_LEN * 1024 * 4);  // 67.1 MB (reused for both layers)
  float* hs0    = (float*)alloc((size_t)T_LEN * 256 * 4);   // 16.8 MB
  float* obs_wT = (float*)alloc(1600 * 128 * 4);
  float* wih0T  = (float*)alloc(192 * 1024 * 4);
  float* wih1T  = (float*)alloc(256 * 1024 * 4);
  float* bias0  = (float*)alloc(1024 * 4);
  float* bias1  = (float*)alloc(1024 * 4);
  float* hbuf   = (float*)alloc(512 * 4);
  unsigned int* cnt = (unsigned int*)alloc((size_t)T_LEN * 4);
  float* h0f = (float*)alloc(256 * 4);
  float* c0f = (float*)alloc(256 * 4);
  float* h1f = (float*)alloc(256 * 4);
  float* c1f = (float*)alloc(256 * 4);

  prep_kernel<<<1024, 256, 0, stream>>>(obs_w, wih0, wih1, bih0, bhh0, bih1, bhh1,
                                        obs_wT, wih0T, wih1T, bias0, bias1);
  encoder_kernel<<<T_LEN / ETS, 256, 0, stream>>>(fov, own_pos, opponent, cost, action,
      conv1_w, conv1_b, conv2_w, conv2_b, obs_wT, obs_b, pos_w, pos_b, opp_w, opp_b,
      act_emb, feat);
  gemm_bias_kernel<<<4096, 256, 0, stream>>>(feat, wih0T, bias0, pre, T_LEN, 1024, 192);
  hipMemsetAsync(cnt, 0, (size_t)T_LEN * 4, stream);
  lstm_layer_kernel<<<64, 256, 0, stream>>>(pre, whh0, hs0, hbuf, cnt, h0f, c0f, 1);
  gemm_bias_kernel<<<4096, 256, 0, stream>>>(hs0, wih1T, bias1, pre, T_LEN, 1024, 256);
  hipMemsetAsync(cnt, 0, (size_t)T_LEN * 4, stream);
  lstm_layer_kernel<<<64, 256, 0, stream>>>(pre, whh1, nullptr, hbuf, cnt, h1f, c1f, 0);
  finalize_kernel<<<5, 256, 0, stream>>>(h0f, c0f, h1f, c1f, (float*)d_out);
}